// Round 1
// baseline (36.594 us; speedup 1.0000x reference)
//
#include <hip/hip_runtime.h>
#include <stdint.h>

// RBF layer: out[b,r] = exp(-0.5 * sum_d ((x[b,d]-c[r,d])^2 / s[r,d]^2)),
// x = l2_normalize(inputs).  Expanded to one bf16 GEMM with K=1600:
//   A_cat[b] = [ x^2 (784) | x (784) | 1, 0..0 (32) ]
//   B_cat[r] = [ w (784)   | -2*c*w (784) | t3, 0..0 (32) ],  w = 1/s^2, t3 = sum c^2 w
//   dist = A_cat · B_cat^T ;  out = exp(-0.5 * dist)

typedef unsigned short u16;
typedef u16   u16x8  __attribute__((ext_vector_type(8)));
typedef u16   u16x4  __attribute__((ext_vector_type(4)));
typedef __bf16 bf16x8 __attribute__((ext_vector_type(8)));
typedef float  f32x4  __attribute__((ext_vector_type(4)));

#define NB 2048
#define NR 256
#define ND 784
#define KC 1600  // 784 + 784 + 32 tail

__device__ __forceinline__ u16 f2bf(float f) {
    union { float f; uint32_t u; } v; v.f = f;
    uint32_t r = v.u + 0x7fffu + ((v.u >> 16) & 1u);  // round-to-nearest-even
    return (u16)(r >> 16);
}

// ---------------- prep: build bf16 operand panels ----------------
// blocks 0..511: 4 input rows each (1 wave/row).  blocks 512..575: 4 center rows each.
__global__ __launch_bounds__(256) void prep_kernel(
        const float* __restrict__ inputs, const float* __restrict__ centers,
        const float* __restrict__ sigmas, u16* __restrict__ Acat, u16* __restrict__ Bcat)
{
    const int w    = threadIdx.x >> 6;
    const int lane = threadIdx.x & 63;
    const int blk  = blockIdx.x;
    if (blk < 512) {
        const int b = blk * 4 + w;
        const float4* src = (const float4*)(inputs + (size_t)b * ND);
        float4 v0 = src[lane];
        float4 v1 = src[lane + 64];
        float4 v2 = src[lane + 128];
        float4 v3 = make_float4(0.f, 0.f, 0.f, 0.f);
        if (lane < 4) v3 = src[lane + 192];           // 784 = 64*3*4 + 16
        float ss = v0.x*v0.x + v0.y*v0.y + v0.z*v0.z + v0.w*v0.w
                 + v1.x*v1.x + v1.y*v1.y + v1.z*v1.z + v1.w*v1.w
                 + v2.x*v2.x + v2.y*v2.y + v2.z*v2.z + v2.w*v2.w
                 + v3.x*v3.x + v3.y*v3.y + v3.z*v3.z + v3.w*v3.w;
        #pragma unroll
        for (int m = 32; m; m >>= 1) ss += __shfl_xor(ss, m);
        const float inv = rsqrtf(fmaxf(ss, 1e-12f));
        u16* rowA = Acat + (size_t)b * KC;
        auto wrA = [&](int col, float4 v) {
            float x0 = v.x*inv, x1 = v.y*inv, x2 = v.z*inv, x3 = v.w*inv;
            u16x4 q2 = { f2bf(x0*x0), f2bf(x1*x1), f2bf(x2*x2), f2bf(x3*x3) };
            u16x4 q1 = { f2bf(x0),    f2bf(x1),    f2bf(x2),    f2bf(x3)    };
            *(u16x4*)(rowA + col)      = q2;
            *(u16x4*)(rowA + ND + col) = q1;
        };
        wrA(4*lane, v0);
        wrA(4*(lane+64), v1);
        wrA(4*(lane+128), v2);
        if (lane < 4) wrA(4*(lane+192), v3);
        if (lane < 8) {                                // tail: [1, 0 x31]
            u16x4 t = {0,0,0,0};
            if (lane == 0) t.x = 0x3F80;               // bf16 1.0
            *(u16x4*)(rowA + 2*ND + 4*lane) = t;
        }
    } else {
        const int r = (blk - 512) * 4 + w;
        const float4* cp = (const float4*)(centers + (size_t)r * ND);
        const float4* sp = (const float4*)(sigmas  + (size_t)r * ND);
        u16* rowB = Bcat + (size_t)r * KC;
        float t3 = 0.f;
        auto wrB = [&](int col, float4 c, float4 s) {
            float w0 = 1.f/(s.x*s.x), w1 = 1.f/(s.y*s.y), w2 = 1.f/(s.z*s.z), w3 = 1.f/(s.w*s.w);
            float c0 = c.x*w0, c1 = c.y*w1, c2 = c.z*w2, c3 = c.w*w3;
            t3 += c.x*c0 + c.y*c1 + c.z*c2 + c.w*c3;
            u16x4 qw = { f2bf(w0), f2bf(w1), f2bf(w2), f2bf(w3) };
            u16x4 qm = { f2bf(-2.f*c0), f2bf(-2.f*c1), f2bf(-2.f*c2), f2bf(-2.f*c3) };
            *(u16x4*)(rowB + col)      = qw;
            *(u16x4*)(rowB + ND + col) = qm;
        };
        wrB(4*lane,       cp[lane],     sp[lane]);
        wrB(4*(lane+64),  cp[lane+64],  sp[lane+64]);
        wrB(4*(lane+128), cp[lane+128], sp[lane+128]);
        if (lane < 4) wrB(4*(lane+192), cp[lane+192], sp[lane+192]);
        #pragma unroll
        for (int m = 32; m; m >>= 1) t3 += __shfl_xor(t3, m);
        if (lane < 8) {                                // tail: [t3, 0 x31]
            u16x4 t = {0,0,0,0};
            if (lane == 0) t.x = f2bf(t3);
            *(u16x4*)(rowB + 2*ND + 4*lane) = t;
        }
    }
}

// ---------------- GEMM: 128 blocks x 4 waves; wave = 32M x 32N; no LDS ----------------
// Frag read pattern (row = lane&15, 16B slot = lane>>4) touches 16 fully-used 64B
// lines per tile -> BW-optimal straight from L2; no barriers anywhere.
__global__ __launch_bounds__(256) void rbf_gemm(
        const u16* __restrict__ Acat, const u16* __restrict__ Bcat, float* __restrict__ out)
{
    const int w    = threadIdx.x >> 6;
    const int lane = threadIdx.x & 63;
    const int wm = (int)(blockIdx.x >> 2) * 64 + (w >> 1) * 32;  // batch rows
    const int wn = (int)(blockIdx.x & 3)  * 64 + (w & 1)  * 32;  // center rows
    const int r16 = lane & 15;
    const int ko  = (lane >> 4) * 8;

    const u16* a0p = Acat + (size_t)(wm + r16) * KC + ko;
    const u16* a1p = a0p + 16 * KC;
    const u16* b0p = Bcat + (size_t)(wn + r16) * KC + ko;
    const u16* b1p = b0p + 16 * KC;

    f32x4 acc00 = {0,0,0,0}, acc01 = {0,0,0,0}, acc10 = {0,0,0,0}, acc11 = {0,0,0,0};
    u16x8 a0A, a1A, b0A, b1A, a0B, a1B, b0B, b1B;

#define LDSET(S, ks) do { const int o_ = (ks) * 32;                         \
    a0##S = *(const u16x8*)(a0p + o_); a1##S = *(const u16x8*)(a1p + o_);   \
    b0##S = *(const u16x8*)(b0p + o_); b1##S = *(const u16x8*)(b1p + o_); } while (0)

#define MM(S) do {                                                                         \
    acc00 = __builtin_amdgcn_mfma_f32_16x16x32_bf16(__builtin_bit_cast(bf16x8, a0##S),     \
                __builtin_bit_cast(bf16x8, b0##S), acc00, 0, 0, 0);                        \
    acc01 = __builtin_amdgcn_mfma_f32_16x16x32_bf16(__builtin_bit_cast(bf16x8, a0##S),     \
                __builtin_bit_cast(bf16x8, b1##S), acc01, 0, 0, 0);                        \
    acc10 = __builtin_amdgcn_mfma_f32_16x16x32_bf16(__builtin_bit_cast(bf16x8, a1##S),     \
                __builtin_bit_cast(bf16x8, b0##S), acc10, 0, 0, 0);                        \
    acc11 = __builtin_amdgcn_mfma_f32_16x16x32_bf16(__builtin_bit_cast(bf16x8, a1##S),     \
                __builtin_bit_cast(bf16x8, b1##S), acc11, 0, 0, 0); } while (0)

    LDSET(A, 0);
    LDSET(B, 1);
    for (int ks = 0; ks < 50; ks += 2) {      // K = 1600 = 50 steps of 32
        MM(A);
        if (ks + 2 < 50) LDSET(A, ks + 2);
        MM(B);
        if (ks + 3 < 50) LDSET(B, ks + 3);
    }

    // C/D layout (verified m89): col = lane&15, row = (lane>>4)*4 + reg
#define STORE(ACC, MO, NO) do {                                   \
    const int row_ = wm + (MO) + ((lane >> 4) << 2);              \
    const int col_ = wn + (NO) + (lane & 15);                     \
    float* o_ = out + (size_t)row_ * NR + col_;                   \
    o_[0]      = __expf(-0.5f * ACC[0]);                          \
    o_[NR]     = __expf(-0.5f * ACC[1]);                          \
    o_[2*NR]   = __expf(-0.5f * ACC[2]);                          \
    o_[3*NR]   = __expf(-0.5f * ACC[3]); } while (0)

    STORE(acc00, 0, 0);  STORE(acc01, 0, 16);
    STORE(acc10, 16, 0); STORE(acc11, 16, 16);
#undef LDSET
#undef MM
#undef STORE
}

extern "C" void kernel_launch(void* const* d_in, const int* in_sizes, int n_in,
                              void* d_out, int out_size, void* d_ws, size_t ws_size,
                              hipStream_t stream) {
    const float* inputs  = (const float*)d_in[0];
    const float* centers = (const float*)d_in[1];
    const float* sigmas  = (const float*)d_in[2];
    u16* Acat = (u16*)d_ws;                       // 2048*1600*2 = 6.55 MB
    u16* Bcat = Acat + (size_t)NB * KC;           // + 256*1600*2 = 0.82 MB (7.4 MB total)
    prep_kernel<<<576, 256, 0, stream>>>(inputs, centers, sigmas, Acat, Bcat);
    rbf_gemm<<<128, 256, 0, stream>>>(Acat, Bcat, (float*)d_out);
}

// Round 2
// 25.563 us; speedup vs baseline: 1.4315x; 1.4315x over previous
//
#include <hip/hip_runtime.h>
#include <stdint.h>

// RBF layer: out[b,r] = exp(-0.5 * sum_d ((x[b,d]-c[r,d])^2 / s[r,d]^2)),
// x = l2_normalize(inputs).  Expanded to one bf16 GEMM with K=1600:
//   A_cat[b] = [ x^2 (784) | x (784) | 1, 0..0 (32) ]
//   B_cat[r] = [ w (784)   | -2*c*w (784) | t3, 0..0 (32) ],  w = 1/s^2, t3 = sum c^2 w
//   dist = A_cat · B_cat^T ;  out = exp(-0.5 * dist)

typedef unsigned short u16;
typedef u16   u16x8  __attribute__((ext_vector_type(8)));
typedef u16   u16x4  __attribute__((ext_vector_type(4)));
typedef __bf16 bf16x8 __attribute__((ext_vector_type(8)));
typedef float  f32x4  __attribute__((ext_vector_type(4)));

#define NB 2048
#define NR 256
#define ND 784
#define KC 1600    // 784 + 784 + 32 tail
#define NSTEP 50   // K-steps of 32
#define PF 5       // prefetch depth in K-steps (cover ~5*78 cyc >= L3 latency)

__device__ __forceinline__ u16 f2bf(float f) {
    union { float f; uint32_t u; } v; v.f = f;
    uint32_t r = v.u + 0x7fffu + ((v.u >> 16) & 1u);  // round-to-nearest-even
    return (u16)(r >> 16);
}

// ---------------- prep: build bf16 operand panels ----------------
// blocks 0..511: 4 input rows each (1 wave/row).  blocks 512..575: 4 center rows each.
__global__ __launch_bounds__(256) void prep_kernel(
        const float* __restrict__ inputs, const float* __restrict__ centers,
        const float* __restrict__ sigmas, u16* __restrict__ Acat, u16* __restrict__ Bcat)
{
    const int w    = threadIdx.x >> 6;
    const int lane = threadIdx.x & 63;
    const int blk  = blockIdx.x;
    if (blk < 512) {
        const int b = blk * 4 + w;
        const float4* src = (const float4*)(inputs + (size_t)b * ND);
        float4 v0 = src[lane];
        float4 v1 = src[lane + 64];
        float4 v2 = src[lane + 128];
        float4 v3 = make_float4(0.f, 0.f, 0.f, 0.f);
        if (lane < 4) v3 = src[lane + 192];           // 784 = 64*3*4 + 16
        float ss = v0.x*v0.x + v0.y*v0.y + v0.z*v0.z + v0.w*v0.w
                 + v1.x*v1.x + v1.y*v1.y + v1.z*v1.z + v1.w*v1.w
                 + v2.x*v2.x + v2.y*v2.y + v2.z*v2.z + v2.w*v2.w
                 + v3.x*v3.x + v3.y*v3.y + v3.z*v3.z + v3.w*v3.w;
        #pragma unroll
        for (int m = 32; m; m >>= 1) ss += __shfl_xor(ss, m);
        const float inv = rsqrtf(fmaxf(ss, 1e-12f));
        u16* rowA = Acat + (size_t)b * KC;
        auto wrA = [&](int col, float4 v) {
            float x0 = v.x*inv, x1 = v.y*inv, x2 = v.z*inv, x3 = v.w*inv;
            u16x4 q2 = { f2bf(x0*x0), f2bf(x1*x1), f2bf(x2*x2), f2bf(x3*x3) };
            u16x4 q1 = { f2bf(x0),    f2bf(x1),    f2bf(x2),    f2bf(x3)    };
            *(u16x4*)(rowA + col)      = q2;
            *(u16x4*)(rowA + ND + col) = q1;
        };
        wrA(4*lane, v0);
        wrA(4*(lane+64), v1);
        wrA(4*(lane+128), v2);
        if (lane < 4) wrA(4*(lane+192), v3);
        if (lane < 8) {                                // tail: [1, 0 x31]
            u16x4 t = {0,0,0,0};
            if (lane == 0) t.x = 0x3F80;               // bf16 1.0
            *(u16x4*)(rowA + 2*ND + 4*lane) = t;
        }
    } else {
        const int r = (blk - 512) * 4 + w;
        const float4* cp = (const float4*)(centers + (size_t)r * ND);
        const float4* sp = (const float4*)(sigmas  + (size_t)r * ND);
        u16* rowB = Bcat + (size_t)r * KC;
        float t3 = 0.f;
        auto wrB = [&](int col, float4 c, float4 s) {
            float w0 = 1.f/(s.x*s.x), w1 = 1.f/(s.y*s.y), w2 = 1.f/(s.z*s.z), w3 = 1.f/(s.w*s.w);
            float c0 = c.x*w0, c1 = c.y*w1, c2 = c.z*w2, c3 = c.w*w3;
            t3 += c.x*c0 + c.y*c1 + c.z*c2 + c.w*c3;
            u16x4 qw = { f2bf(w0), f2bf(w1), f2bf(w2), f2bf(w3) };
            u16x4 qm = { f2bf(-2.f*c0), f2bf(-2.f*c1), f2bf(-2.f*c2), f2bf(-2.f*c3) };
            *(u16x4*)(rowB + col)      = qw;
            *(u16x4*)(rowB + ND + col) = qm;
        };
        wrB(4*lane,       cp[lane],     sp[lane]);
        wrB(4*(lane+64),  cp[lane+64],  sp[lane+64]);
        wrB(4*(lane+128), cp[lane+128], sp[lane+128]);
        if (lane < 4) wrB(4*(lane+192), cp[lane+192], sp[lane+192]);
        #pragma unroll
        for (int m = 32; m; m >>= 1) t3 += __shfl_xor(t3, m);
        if (lane < 8) {                                // tail: [t3, 0 x31]
            u16x4 t = {0,0,0,0};
            if (lane == 0) t.x = f2bf(t3);
            *(u16x4*)(rowB + 2*ND + 4*lane) = t;
        }
    }
}

// ---------------- GEMM: 512 blocks x 1 wave; wave = 32M x 32N; no LDS ----------------
// 512 single-wave blocks -> 2 blocks/CU, all 256 CUs busy.  5-deep K-step prefetch
// pipeline (statically indexed buffers) covers ~390 SIMD-cycles, >= L2/L3 hit latency.
// XCD swizzle: each XCD owns a contiguous 256-row A band (0.82 MB) + whole B (0.82 MB),
// both resident in its 4 MB L2.
__global__ __launch_bounds__(64) void rbf_gemm(
        const u16* __restrict__ Acat, const u16* __restrict__ Bcat, float* __restrict__ out)
{
    const int lane = threadIdx.x;
    const int bid  = (int)blockIdx.x;
    const int tile = (bid & 7) * 64 + (bid >> 3);   // bijective (512 % 8 == 0)
    const int wm = (tile >> 3) * 32;                 // batch rows
    const int wn = (tile & 7) * 32;                  // center rows
    const int r16 = lane & 15;
    const int ko  = (lane >> 4) * 8;

    const u16* a0p = Acat + (size_t)(wm + r16) * KC + ko;
    const u16* a1p = a0p + 16 * KC;
    const u16* b0p = Bcat + (size_t)(wn + r16) * KC + ko;
    const u16* b1p = b0p + 16 * KC;

    f32x4 acc00 = {0,0,0,0}, acc01 = {0,0,0,0}, acc10 = {0,0,0,0}, acc11 = {0,0,0,0};
    u16x8 a0[PF], a1[PF], b0[PF], b1[PF];

#define LDSET(J, KS) do { const int o_ = (KS) * 32;                           \
    a0[J] = *(const u16x8*)(a0p + o_); a1[J] = *(const u16x8*)(a1p + o_);     \
    b0[J] = *(const u16x8*)(b0p + o_); b1[J] = *(const u16x8*)(b1p + o_); } while (0)

#define MM(J) do {                                                                        \
    acc00 = __builtin_amdgcn_mfma_f32_16x16x32_bf16(__builtin_bit_cast(bf16x8, a0[J]),    \
                __builtin_bit_cast(bf16x8, b0[J]), acc00, 0, 0, 0);                       \
    acc01 = __builtin_amdgcn_mfma_f32_16x16x32_bf16(__builtin_bit_cast(bf16x8, a0[J]),    \
                __builtin_bit_cast(bf16x8, b1[J]), acc01, 0, 0, 0);                       \
    acc10 = __builtin_amdgcn_mfma_f32_16x16x32_bf16(__builtin_bit_cast(bf16x8, a1[J]),    \
                __builtin_bit_cast(bf16x8, b0[J]), acc10, 0, 0, 0);                       \
    acc11 = __builtin_amdgcn_mfma_f32_16x16x32_bf16(__builtin_bit_cast(bf16x8, a1[J]),    \
                __builtin_bit_cast(bf16x8, b1[J]), acc11, 0, 0, 0); } while (0)

    #pragma unroll
    for (int j = 0; j < PF; ++j) LDSET(j, j);        // prologue: steps 0..4 in flight

    for (int base = 0; base < NSTEP - PF; base += PF) {   // 9 iterations
        #pragma unroll
        for (int j = 0; j < PF; ++j) {
            MM(j);
            LDSET(j, base + PF + j);                  // refill slot 5 steps ahead
        }
    }
    #pragma unroll
    for (int j = 0; j < PF; ++j) MM(j);               // epilogue: steps 45..49

    // C/D layout (verified m89): col = lane&15, row = (lane>>4)*4 + reg
#define STORE(ACC, MO, NO) do {                                   \
    const int row_ = wm + (MO) + ((lane >> 4) << 2);              \
    const int col_ = wn + (NO) + (lane & 15);                     \
    float* o_ = out + (size_t)row_ * NR + col_;                   \
    o_[0]      = __expf(-0.5f * ACC[0]);                          \
    o_[NR]     = __expf(-0.5f * ACC[1]);                          \
    o_[2*NR]   = __expf(-0.5f * ACC[2]);                          \
    o_[3*NR]   = __expf(-0.5f * ACC[3]); } while (0)

    STORE(acc00, 0, 0);  STORE(acc01, 0, 16);
    STORE(acc10, 16, 0); STORE(acc11, 16, 16);
#undef LDSET
#undef MM
#undef STORE
}

extern "C" void kernel_launch(void* const* d_in, const int* in_sizes, int n_in,
                              void* d_out, int out_size, void* d_ws, size_t ws_size,
                              hipStream_t stream) {
    const float* inputs  = (const float*)d_in[0];
    const float* centers = (const float*)d_in[1];
    const float* sigmas  = (const float*)d_in[2];
    u16* Acat = (u16*)d_ws;                       // 2048*1600*2 = 6.55 MB
    u16* Bcat = Acat + (size_t)NB * KC;           // + 256*1600*2 = 0.82 MB (7.4 MB total)
    prep_kernel<<<576, 256, 0, stream>>>(inputs, centers, sigmas, Acat, Bcat);
    rbf_gemm<<<512, 64, 0, stream>>>(Acat, Bcat, (float*)d_out);
}